// Round 7
// baseline (347.884 us; speedup 1.0000x reference)
//
#include <hip/hip_runtime.h>
#include <hip/hip_bf16.h>

// Problem constants (from reference)
#define NB 4       // batch
#define CIN 32
#define TT 8       // time steps
#define NN 2000    // nodes
#define NE 16000   // edges
#define H1C 128
#define H2C 256
#define COUT 64
#define BT (NB*TT) // 32 graph replicas
#define ROW 2048   // padded LDS row stride (floats)

// =============== kernel 1: everything except the final GEMM ===============
// grid (8, 33), 1024 threads:
//   blockIdx.y < 32 : gather blocks — (channel-group cg=blockIdx.x, bt=blockIdx.y)
//                     compute C3[bt][cg*4..cg*4+3][:] = (S^3 x)        via
//                     S^3 = D^-1/2 [(A+I)D^-1]^3 D^1/2 — 3 edge-parallel
//                     LDS scatter passes, no CSR needed.
//   blockIdx.y ==32 : 8 weight-folding blocks (j0 = blockIdx.x*8)
//   block (0,0)     : also emits r1 = S*1, r2 = S*r1 (rank-1 bias terms)
__global__ __launch_bounds__(1024) void k_sss(
    const float* __restrict__ x,
    const int* __restrict__ src, const int* __restrict__ dst,
    const float* __restrict__ ew,
    const float* __restrict__ W1, const float* __restrict__ b1,
    const float* __restrict__ W2, const float* __restrict__ b2,
    const float* __restrict__ W3,
    float* __restrict__ r1f, float* __restrict__ r2f,
    float* __restrict__ W123_g, float* __restrict__ d1_g, float* __restrict__ d2_g,
    float* __restrict__ C3)     // [bt][32][2000] channel-major
{
    extern __shared__ float smem[];
    const int tid = threadIdx.x;

    if (blockIdx.y == 32) {
        // ---------- weight folding, 8-column slice ----------
        float* W3s  = smem;            // [256][8]
        float* W23s = smem + H2C * 8;  // [129][8]: rows 0..127 = W2@W3, row 128 = b2@W3
        const int j0 = blockIdx.x * 8;

        for (int i = tid; i < H2C * 8; i += 1024)
            W3s[i] = W3[(size_t)(i >> 3) * COUT + j0 + (i & 7)];
        __syncthreads();

        for (int r = tid >> 3; r < H1C + 1; r += 128) {
            int j = tid & 7;
            const float* wrow = (r < H1C) ? (W2 + (size_t)r * H2C) : b2;
            float a0 = 0, a1 = 0, a2 = 0, a3 = 0;
            for (int k = 0; k < H2C; k += 4) {
                float4 wv = *(const float4*)(wrow + k);
                a0 += wv.x * W3s[(k + 0) * 8 + j];
                a1 += wv.y * W3s[(k + 1) * 8 + j];
                a2 += wv.z * W3s[(k + 2) * 8 + j];
                a3 += wv.w * W3s[(k + 3) * 8 + j];
            }
            W23s[r * 8 + j] = (a0 + a1) + (a2 + a3);
        }
        __syncthreads();

        for (int r = tid >> 3; r < CIN + 1; r += 128) {
            int j = tid & 7;
            const float* wrow = (r < CIN) ? (W1 + (size_t)r * H1C) : b1;
            float a0 = 0, a1 = 0, a2 = 0, a3 = 0;
            for (int k = 0; k < H1C; k += 4) {
                float4 wv = *(const float4*)(wrow + k);
                a0 += wv.x * W23s[(k + 0) * 8 + j];
                a1 += wv.y * W23s[(k + 1) * 8 + j];
                a2 += wv.z * W23s[(k + 2) * 8 + j];
                a3 += wv.w * W23s[(k + 3) * 8 + j];
            }
            float acc = (a0 + a1) + (a2 + a3);
            if (r < CIN) W123_g[(size_t)r * COUT + j0 + j] = acc;
            else         d1_g[j0 + j] = acc;
        }
        if (tid < 8) d2_g[j0 + tid] = W23s[H1C * 8 + tid];
        return;
    }

    // ---------- gather block ----------
    float* A   = smem;             // 4 x ROW   (channel rows, bank = n%32)
    float* Bf  = smem + 4 * ROW;   // 4 x ROW
    float* idg = smem + 8 * ROW;   // ROW: holds deg, then 1/deg

    const int cg = blockIdx.x, bt = blockIdx.y;
    const int b = bt >> 3, t = bt & 7;

    // deg (incl self-loop weight 1), per-block redundant — no prep kernel
    for (int i = tid; i < ROW; i += 1024) idg[i] = 1.0f;
    __syncthreads();
    for (int e = tid; e < NE; e += 1024)
        atomicAdd(&idg[dst[e]], ew[e]);
    __syncthreads();
    for (int i = tid; i < ROW; i += 1024) idg[i] = 1.0f / idg[i];
    __syncthreads();

    // stage x: Z0 = x * sqrt(deg) = x * rsqrt(idg)
    #pragma unroll
    for (int c = 0; c < 4; c++) {
        const float* xr = x + (((size_t)b * CIN + cg * 4 + c) * TT + t) * NN;
        for (int i = tid; i < NN; i += 1024)
            A[c * ROW + i] = xr[i] * rsqrtf(idg[i]);
    }

    // block (0,0) side job: r1 = S*1, r2 = S*r1 (uses Bf rows as temps)
    if (cg == 0 && bt == 0) {
        float* t1 = Bf;
        float* t2 = Bf + ROW;
        for (int n = tid; n < NN; n += 1024) t1[n] = sqrtf(idg[n]);   // dinv
        __syncthreads();
        for (int e = tid; e < NE; e += 1024)
            atomicAdd(&t1[dst[e]], ew[e] * sqrtf(idg[src[e]]));
        __syncthreads();
        for (int n = tid; n < NN; n += 1024) {
            float r = sqrtf(idg[n]) * t1[n];
            r1f[n] = r; t1[n] = r;
        }
        __syncthreads();
        for (int n = tid; n < NN; n += 1024) t2[n] = sqrtf(idg[n]) * t1[n];
        __syncthreads();
        for (int e = tid; e < NE; e += 1024) {
            int s = src[e];
            atomicAdd(&t2[dst[e]], ew[e] * sqrtf(idg[s]) * t1[s]);
        }
        __syncthreads();
        for (int n = tid; n < NN; n += 1024) r2f[n] = sqrtf(idg[n]) * t2[n];
    }
    __syncthreads();

    // three passes of P = (A+I)D^-1 : scale -> copy(self) -> edge scatter
    float* S = A; float* D = Bf;
    for (int pass = 0; pass < 3; pass++) {
        for (int i = tid; i < 4 * ROW; i += 1024) {
            float v = S[i] * idg[i & (ROW - 1)];
            S[i] = v;        // Zs
            D[i] = v;        // self term init
        }
        __syncthreads();
        #pragma unroll 2
        for (int e = tid; e < NE; e += 1024) {
            int s_ = src[e], d_ = dst[e];
            float w = ew[e];
            atomicAdd(&D[0 * ROW + d_], w * S[0 * ROW + s_]);
            atomicAdd(&D[1 * ROW + d_], w * S[1 * ROW + s_]);
            atomicAdd(&D[2 * ROW + d_], w * S[2 * ROW + s_]);
            atomicAdd(&D[3 * ROW + d_], w * S[3 * ROW + s_]);
        }
        __syncthreads();
        float* tmp = S; S = D; D = tmp;
    }

    // store C3 = result * dinv, dinv = sqrt(idg)
    #pragma unroll
    for (int c = 0; c < 4; c++) {
        float* orow = C3 + ((size_t)bt * CIN + cg * 4 + c) * NN;
        for (int i = tid; i < NN; i += 1024)
            orow[i] = S[c * ROW + i] * sqrtf(idg[i]);
    }
}

// =============== kernel 2: P = C3@W123 + r2*d1 + r1*d2 + b3; out = relu(P), transposed ===============
__global__ __launch_bounds__(256) void k_out(
    const float* __restrict__ C3,       // [bt][32][2000]
    const float* __restrict__ W123,     // 32x64
    const float* __restrict__ d1, const float* __restrict__ d2,
    const float* __restrict__ b3,
    const float* __restrict__ r1f, const float* __restrict__ r2f,
    float* __restrict__ out)            // [B][COUT][T][N]
{
    __shared__ float Cs[CIN][65];
    __shared__ float Ws[CIN][64];
    __shared__ float Os[64][65];
    __shared__ float d1s[64], d2s[64], b3s[64], r1s[64], r2s[64];
    const int tid = threadIdx.x;
    const int bt = blockIdx.y, b = bt >> 3, t = bt & 7;
    const int n0 = blockIdx.x * 64;

    for (int i = tid; i < CIN * 64; i += 256) {
        int ch = i >> 6, nn = i & 63;
        int n = n0 + nn;
        Cs[ch][nn] = (n < NN) ? C3[((size_t)bt * CIN + ch) * NN + n] : 0.f;
    }
    for (int i = tid; i < CIN * 64; i += 256)
        Ws[i >> 6][i & 63] = W123[i];
    if (tid < 64) {
        d1s[tid] = d1[tid];
        d2s[tid] = d2[tid];
        b3s[tid] = b3[tid];
        int n = n0 + tid;
        r1s[tid] = (n < NN) ? r1f[n] : 0.f;
        r2s[tid] = (n < NN) ? r2f[n] : 0.f;
    }
    __syncthreads();

    const int c = tid & 63, g = tid >> 6;
    for (int i = 0; i < 16; i++) {
        int nn = g * 16 + i;
        float acc = r2s[nn] * d1s[c] + r1s[nn] * d2s[c] + b3s[c];
        #pragma unroll
        for (int k = 0; k < CIN; k++) acc += Cs[k][nn] * Ws[k][c];
        Os[nn][c] = fmaxf(acc, 0.f);
    }
    __syncthreads();

    #pragma unroll
    for (int pass = 0; pass < 16; pass++) {
        int cc = g + pass * 4;
        int n = n0 + (tid & 63);
        if (n < NN)
            out[(((size_t)b * COUT + cc) * TT + t) * NN + n] = Os[tid & 63][cc];
    }
}

// ---------------- launch ----------------

extern "C" void kernel_launch(void* const* d_in, const int* in_sizes, int n_in,
                              void* d_out, int out_size, void* d_ws, size_t ws_size,
                              hipStream_t stream) {
    (void)in_sizes; (void)n_in; (void)out_size; (void)ws_size;

    const float* x  = (const float*)d_in[0];
    const int*   ei = (const int*)d_in[1];
    const float* ew = (const float*)d_in[2];
    const float* W1 = (const float*)d_in[3];
    const float* b1 = (const float*)d_in[4];
    const float* W2 = (const float*)d_in[5];
    const float* b2 = (const float*)d_in[6];
    const float* W3 = (const float*)d_in[7];
    const float* b3 = (const float*)d_in[8];
    float* out = (float*)d_out;

    const int* src = ei;
    const int* dst = ei + NE;

    // workspace layout (float units)
    float* ws   = (float*)d_ws;
    float* r1f  = ws;            // 2048
    float* r2f  = ws + 2048;     // 2048
    float* W123 = ws + 4096;     // 2048
    float* d1   = ws + 6144;     // 64
    float* d2   = ws + 6208;     // 64
    float* C3   = ws + 6272;     // 32*32*2000 floats

    const size_t lds_sss = (size_t)(9 * ROW) * sizeof(float);   // 73728 B

    k_sss<<<dim3(8, 33), dim3(1024), lds_sss, stream>>>(
        x, src, dst, ew, W1, b1, W2, b2, W3,
        r1f, r2f, W123, d1, d2, C3);

    k_out<<<dim3(32, BT), dim3(256), 0, stream>>>(
        C3, W123, d1, d2, b3, r1f, r2f, out);
}

// Round 9
// 76.411 us; speedup vs baseline: 4.5528x; 4.5528x over previous
//
#include <hip/hip_runtime.h>
#include <hip/hip_bf16.h>

// Problem constants (from reference)
#define NB 4       // batch
#define CIN 32
#define TT 8       // time steps
#define NN 2000    // nodes
#define NE 16000   // edges
#define H1C 128
#define H2C 256
#define COUT 64
#define BT (NB*TT) // 32 graph replicas
#define RS 2049    // LDS row stride in floats (2049%32==1 -> channels hit distinct banks)

#define FSCALE 262144.0f            // 2^18 fixed-point scale for scatter accum
#define FINV   (1.0f/262144.0f)
#define DSCALE 16777216.0f          // 2^24 for degree accumulation (ew in [0,1])
#define DINV   (1.0f/16777216.0f)

// =============== kernel 1: S^3*X + weight folding + rank-1 bias vectors ===============
// grid (9, 33), 1024 threads:
//   x<8,  y<32 : gather blocks (cg=x, bt=y): C3[bt][4cg..4cg+3][:] = S^3 x  via
//                S^3 = D^-1/2 [(A+I)D^-1]^3 D^1/2, 3 edge-parallel scatter passes
//                with native INT LDS atomics (fixed-point).
//   x<8,  y==32: weight folding, 8-column slice j0 = x*8
//   x==8, y==32: r1 = S*1, r2 = S*r1 (int-scatter)
//   x==8, y<32 : no-op
__global__ __launch_bounds__(1024) void k_sss(
    const float* __restrict__ x,
    const int* __restrict__ src, const int* __restrict__ dst,
    const float* __restrict__ ew,
    const float* __restrict__ W1, const float* __restrict__ b1,
    const float* __restrict__ W2, const float* __restrict__ b2,
    const float* __restrict__ W3,
    float* __restrict__ r1f, float* __restrict__ r2f,
    float* __restrict__ W123_g, float* __restrict__ d1_g, float* __restrict__ d2_g,
    float* __restrict__ C3)     // [bt][32][2000] channel-major
{
    extern __shared__ float smem[];
    const int tid = threadIdx.x;
    const int bx = blockIdx.x, by = blockIdx.y;

    if (bx == 8) {
        if (by != 32) return;
        // ---------- r1/r2 block ----------
        int*   degi = (int*)smem;            // RS
        float* t1   = smem + RS;             // RS
        int*   ti   = (int*)(smem + 2 * RS); // RS

        for (int i = tid; i < NN; i += 1024) degi[i] = 0;
        __syncthreads();
        for (int e = tid; e < NE; e += 1024)
            atomicAdd(&degi[dst[e]], __float2int_rn(ew[e] * DSCALE));
        __syncthreads();
        // r1 = S*1: per-src value u = dinv (self term incl.)
        for (int n = tid; n < NN; n += 1024) {
            float dv = 1.0f / sqrtf(1.0f + degi[n] * DINV);
            t1[n] = dv;
            ti[n] = __float2int_rn(dv * FSCALE);
        }
        __syncthreads();
        for (int e = tid; e < NE; e += 1024)
            atomicAdd(&ti[dst[e]], __float2int_rn(ew[e] * t1[src[e]] * FSCALE));
        __syncthreads();
        for (int n = tid; n < NN; n += 1024) {
            float dv = 1.0f / sqrtf(1.0f + degi[n] * DINV);
            float r = dv * (ti[n] * FINV);
            r1f[n] = r;
            t1[n] = dv * r;          // per-src value for r2 pass
        }
        __syncthreads();
        for (int n = tid; n < NN; n += 1024)
            ti[n] = __float2int_rn(t1[n] * FSCALE);
        __syncthreads();
        for (int e = tid; e < NE; e += 1024)
            atomicAdd(&ti[dst[e]], __float2int_rn(ew[e] * t1[src[e]] * FSCALE));
        __syncthreads();
        for (int n = tid; n < NN; n += 1024) {
            float dv = 1.0f / sqrtf(1.0f + degi[n] * DINV);
            r2f[n] = dv * (ti[n] * FINV);
        }
        return;
    }

    if (by == 32) {
        // ---------- weight folding, 8-column slice ----------
        float* W3s  = smem;            // [256][8]
        float* W23s = smem + H2C * 8;  // [129][8]: rows 0..127 = W2@W3, row 128 = b2@W3
        const int j0 = bx * 8;

        for (int i = tid; i < H2C * 8; i += 1024)
            W3s[i] = W3[(size_t)(i >> 3) * COUT + j0 + (i & 7)];
        __syncthreads();

        for (int r = tid >> 3; r < H1C + 1; r += 128) {
            int j = tid & 7;
            const float* wrow = (r < H1C) ? (W2 + (size_t)r * H2C) : b2;
            float a0 = 0, a1 = 0, a2 = 0, a3 = 0;
            for (int k = 0; k < H2C; k += 4) {
                float4 wv = *(const float4*)(wrow + k);
                a0 += wv.x * W3s[(k + 0) * 8 + j];
                a1 += wv.y * W3s[(k + 1) * 8 + j];
                a2 += wv.z * W3s[(k + 2) * 8 + j];
                a3 += wv.w * W3s[(k + 3) * 8 + j];
            }
            W23s[r * 8 + j] = (a0 + a1) + (a2 + a3);
        }
        __syncthreads();

        for (int r = tid >> 3; r < CIN + 1; r += 128) {
            int j = tid & 7;
            const float* wrow = (r < CIN) ? (W1 + (size_t)r * H1C) : b1;
            float a0 = 0, a1 = 0, a2 = 0, a3 = 0;
            for (int k = 0; k < H1C; k += 4) {
                float4 wv = *(const float4*)(wrow + k);
                a0 += wv.x * W23s[(k + 0) * 8 + j];
                a1 += wv.y * W23s[(k + 1) * 8 + j];
                a2 += wv.z * W23s[(k + 2) * 8 + j];
                a3 += wv.w * W23s[(k + 3) * 8 + j];
            }
            float acc = (a0 + a1) + (a2 + a3);
            if (r < CIN) W123_g[(size_t)r * COUT + j0 + j] = acc;
            else         d1_g[j0 + j] = acc;
        }
        if (tid < 8) d2_g[j0 + tid] = W23s[H1C * 8 + tid];
        return;
    }

    // ---------- gather block ----------
    float* Sf  = smem;                    // 4 x RS floats (current values, read side)
    int*   Di  = (int*)(smem + 4 * RS);   // 4 x RS int   (scatter accumulators)
    float* idg = smem + 8 * RS;           // RS: 1/deg
    int*   degi = (int*)idg;

    const int cg = bx, bt = by;
    const int b = bt >> 3, t = bt & 7;

    // per-block degree (int fixed-point; no prep kernel, no float atomics)
    for (int i = tid; i < NN; i += 1024) degi[i] = 0;
    __syncthreads();
    for (int e = tid; e < NE; e += 1024)
        atomicAdd(&degi[dst[e]], __float2int_rn(ew[e] * DSCALE));
    __syncthreads();
    for (int i = tid; i < NN; i += 1024)
        idg[i] = 1.0f / (1.0f + degi[i] * DINV);   // in-place int -> float, per-element
    __syncthreads();

    // stage Z0 = x * D^{1/2}
    #pragma unroll
    for (int c = 0; c < 4; c++) {
        const float* xr = x + (((size_t)b * CIN + cg * 4 + c) * TT + t) * NN;
        for (int i = tid; i < NN; i += 1024)
            Sf[c * RS + i] = xr[i] * rsqrtf(idg[i]);
    }
    __syncthreads();

    // three passes of Z' = (A+I) D^-1 Z, int fixed-point scatter
    for (int pass = 0; pass < 3; pass++) {
        #pragma unroll
        for (int c = 0; c < 4; c++)
            for (int i = tid; i < NN; i += 1024) {
                float cur = (pass == 0) ? Sf[c * RS + i] : Di[c * RS + i] * FINV;
                float v = cur * idg[i];
                Sf[c * RS + i] = v;                          // read side (Zs)
                Di[c * RS + i] = __float2int_rn(v * FSCALE); // self-term init
            }
        __syncthreads();
        for (int e = tid; e < NE; e += 1024) {
            int s_ = src[e], d_ = dst[e];
            float w = ew[e];
            #pragma unroll
            for (int c = 0; c < 4; c++)
                atomicAdd(&Di[c * RS + d_],
                          __float2int_rn(w * Sf[c * RS + s_] * FSCALE));
        }
        __syncthreads();
    }

    // store C3 = D^-1/2 * Z3
    #pragma unroll
    for (int c = 0; c < 4; c++) {
        float* orow = C3 + ((size_t)bt * CIN + cg * 4 + c) * NN;
        for (int i = tid; i < NN; i += 1024)
            orow[i] = (Di[c * RS + i] * FINV) * sqrtf(idg[i]);
    }
}

// =============== kernel 2: P = C3@W123 + r2*d1 + r1*d2 + b3; out = relu(P), transposed ===============
__global__ __launch_bounds__(256) void k_out(
    const float* __restrict__ C3,       // [bt][32][2000]
    const float* __restrict__ W123,     // 32x64
    const float* __restrict__ d1, const float* __restrict__ d2,
    const float* __restrict__ b3,
    const float* __restrict__ r1f, const float* __restrict__ r2f,
    float* __restrict__ out)            // [B][COUT][T][N]
{
    __shared__ float Cs[CIN][65];
    __shared__ float Ws[CIN][64];
    __shared__ float Os[64][65];
    __shared__ float d1s[64], d2s[64], b3s[64], r1s[64], r2s[64];
    const int tid = threadIdx.x;
    const int bt = blockIdx.y, b = bt >> 3, t = bt & 7;
    const int n0 = blockIdx.x * 64;

    for (int i = tid; i < CIN * 64; i += 256) {
        int ch = i >> 6, nn = i & 63;
        int n = n0 + nn;
        Cs[ch][nn] = (n < NN) ? C3[((size_t)bt * CIN + ch) * NN + n] : 0.f;
    }
    for (int i = tid; i < CIN * 64; i += 256)
        Ws[i >> 6][i & 63] = W123[i];
    if (tid < 64) {
        d1s[tid] = d1[tid];
        d2s[tid] = d2[tid];
        b3s[tid] = b3[tid];
        int n = n0 + tid;
        r1s[tid] = (n < NN) ? r1f[n] : 0.f;
        r2s[tid] = (n < NN) ? r2f[n] : 0.f;
    }
    __syncthreads();

    const int c = tid & 63, g = tid >> 6;
    for (int i = 0; i < 16; i++) {
        int nn = g * 16 + i;
        float acc = r2s[nn] * d1s[c] + r1s[nn] * d2s[c] + b3s[c];
        #pragma unroll
        for (int k = 0; k < CIN; k++) acc += Cs[k][nn] * Ws[k][c];
        Os[nn][c] = fmaxf(acc, 0.f);
    }
    __syncthreads();

    #pragma unroll
    for (int pass = 0; pass < 16; pass++) {
        int cc = g + pass * 4;
        int n = n0 + (tid & 63);
        if (n < NN)
            out[(((size_t)b * COUT + cc) * TT + t) * NN + n] = Os[tid & 63][cc];
    }
}

// ---------------- launch ----------------

extern "C" void kernel_launch(void* const* d_in, const int* in_sizes, int n_in,
                              void* d_out, int out_size, void* d_ws, size_t ws_size,
                              hipStream_t stream) {
    (void)in_sizes; (void)n_in; (void)out_size; (void)ws_size;

    const float* x  = (const float*)d_in[0];
    const int*   ei = (const int*)d_in[1];
    const float* ew = (const float*)d_in[2];
    const float* W1 = (const float*)d_in[3];
    const float* b1 = (const float*)d_in[4];
    const float* W2 = (const float*)d_in[5];
    const float* b2 = (const float*)d_in[6];
    const float* W3 = (const float*)d_in[7];
    const float* b3 = (const float*)d_in[8];
    float* out = (float*)d_out;

    const int* src = ei;
    const int* dst = ei + NE;

    // workspace layout (float units)
    float* ws   = (float*)d_ws;
    float* r1f  = ws;            // 2048
    float* r2f  = ws + 2048;     // 2048
    float* W123 = ws + 4096;     // 2048
    float* d1   = ws + 6144;     // 64
    float* d2   = ws + 6208;     // 64
    float* C3   = ws + 6272;     // 32*32*2000 floats

    const size_t lds_sss = (size_t)(9 * RS) * sizeof(float);   // 73764 B

    k_sss<<<dim3(9, 33), dim3(1024), lds_sss, stream>>>(
        x, src, dst, ew, W1, b1, W2, b2, W3,
        r1f, r2f, W123, d1, d2, C3);

    k_out<<<dim3(32, BT), dim3(256), 0, stream>>>(
        C3, W123, d1, d2, b3, r1f, r2f, out);
}